// Round 4
// baseline (57.029 us; speedup 1.0000x reference)
//
#include <hip/hip_runtime.h>
#include <hip/hip_bf16.h>

#define B_  4
#define C_  640
#define H_  64
#define W_  64
#define NT1 512          // 8 waves
#define G1  8            // channel groups per block (one wave each)
#define CPG 40           // channels per thread: G1*CPG = 320 = C_/2
#define CHALF 320

// ---------------------------------------------------------------------------
// Block decode shared by the pipeline kernels. grid = 512 linear blocks.
// XCD x owns rows [x*8, x*8+8) for all (b, s): Fwarp row sharing stays in-L2.
// Bijective: n = (b*16 + s*8 + (h&7))*8 + h/8.
__device__ __forceinline__ void decode_bhs(int n, int& b, int& h, int& s) {
    const int xcd = n & 7;
    const int i   = n >> 3;          // 0..63
    h = xcd * 8 + (i & 7);
    s = (i >> 3) & 1;
    b = i >> 4;
}

// ===========================================================================
// K1: partial sim (this block's 320 channels) + partial lamT dot.
//   simp [B][H][2][W][9], lamTp [B][H][2][W]
__global__ __launch_bounds__(NT1, 4) void k1_sim(
    const float* __restrict__ Ft, const float* __restrict__ Fwp,
    const float* __restrict__ cw,
    float* __restrict__ simp, float* __restrict__ lamTp)
{
    __shared__ float lds_sim[G1][W_][9];   // 18 KB
    __shared__ float lds_lamT[G1][W_];     // 2 KB
    __shared__ float lds_cw2[C_];          // 2.5 KB (Ft-half weights)

    const int t = threadIdx.x, w = t & 63, g = t >> 6;
    int b, h, s; decode_bhs(blockIdx.x, b, h, s);
    const int hm = (h > 0) ? h - 1 : 0;
    const int hp = (h < H_ - 1) ? h + 1 : H_ - 1;
    const size_t cs = (size_t)H_ * W_;
    const int c0 = s * CHALF + g * CPG;

    for (int i = t; i < C_; i += NT1) lds_cw2[i] = cw[C_ + i];
    __syncthreads();

    const float* ftp = Ft  + ((size_t)(b * C_ + c0) * H_ + h ) * W_ + w;
    const float* f0p = Fwp + ((size_t)(b * C_ + c0) * H_ + hm) * W_ + w;
    const float* f1p = Fwp + ((size_t)(b * C_ + c0) * H_ + h ) * W_ + w;
    const float* f2p = Fwp + ((size_t)(b * C_ + c0) * H_ + hp) * W_ + w;

    // displaced accumulation: center / right-shifted / left-shifted products
    float sC0=0.f,sC1=0.f,sC2=0.f, sA0=0.f,sA1=0.f,sA2=0.f, sB0=0.f,sB1=0.f,sB2=0.f;
    float lamT = 0.f;
    const int lnL = (w - 1) & 63;
    const int lnR = (w + 1) & 63;

    #pragma unroll 8
    for (int k = 0; k < CPG; ++k) {
        float ft = ftp[k * cs];
        float f0 = f0p[k * cs];
        float f1 = f1p[k * cs];
        float f2 = f2p[k * cs];
        float ftL = __shfl(ft, lnL, 64);
        float ftR = __shfl(ft, lnR, 64);
        sC0 = fmaf(ft , f0, sC0); sC1 = fmaf(ft , f1, sC1); sC2 = fmaf(ft , f2, sC2);
        sA0 = fmaf(ftR, f0, sA0); sA1 = fmaf(ftR, f1, sA1); sA2 = fmaf(ftR, f2, sA2);
        sB0 = fmaf(ftL, f0, sB0); sB1 = fmaf(ftL, f1, sB1); sB2 = fmaf(ftL, f2, sB2);
        lamT = fmaf(lds_cw2[c0 + k], ft, lamT);
    }

    float simn[9];
    simn[1] = sC0; simn[4] = sC1; simn[7] = sC2;
    simn[0] = __shfl(sA0, lnL, 64);
    simn[3] = __shfl(sA1, lnL, 64);
    simn[6] = __shfl(sA2, lnL, 64);
    simn[2] = __shfl(sB0, lnR, 64);
    simn[5] = __shfl(sB1, lnR, 64);
    simn[8] = __shfl(sB2, lnR, 64);
    if (w == 0)      { simn[0] = sC0; simn[3] = sC1; simn[6] = sC2; }  // replicate pad
    if (w == W_ - 1) { simn[2] = sC0; simn[5] = sC1; simn[8] = sC2; }

    #pragma unroll
    for (int q = 0; q < 9; ++q) lds_sim[g][w][q] = simn[q];
    lds_lamT[g][w] = lamT;
    __syncthreads();

    const size_t r2 = ((size_t)(b * H_ + h) * 2 + s);
    float* sp = simp + r2 * (W_ * 9);
    for (int idx = t; idx < W_ * 9; idx += NT1) {
        const int ww = idx / 9, q = idx % 9;
        float v = 0.f;
        #pragma unroll
        for (int gg = 0; gg < G1; ++gg) v += lds_sim[gg][ww][q];
        sp[idx] = v;
    }
    if (t < W_) {
        float v = 0.f;
        #pragma unroll
        for (int gg = 0; gg < G1; ++gg) v += lds_lamT[gg][t];
        lamTp[r2 * W_ + t] = v;
    }
}

// ===========================================================================
// K2: reduce sim halves + mask + softmax (dup per half-block, cheap), then
//     Fw for this block's 320 channels (bf16 -> ws) + partial lamF dot.
__global__ __launch_bounds__(NT1, 4) void k2_fw(
    const float* __restrict__ Fwp, const float* __restrict__ mask,
    const float* __restrict__ cw, const float* __restrict__ simp,
    float* __restrict__ lamFp, __hip_bfloat16* __restrict__ Fww)
{
    __shared__ float lds_attn[W_][9];      // 2.25 KB
    __shared__ float lds_red[G1][W_];      // 2 KB
    __shared__ float lds_cw1[C_];          // 2.5 KB (Fw-half weights)
    __shared__ float lds_msk[3][W_];       // 0.75 KB

    const int t = threadIdx.x, w = t & 63, g = t >> 6;
    int b, h, s; decode_bhs(blockIdx.x, b, h, s);
    const int hm = (h > 0) ? h - 1 : 0;
    const int hp = (h < H_ - 1) ? h + 1 : H_ - 1;
    const size_t cs = (size_t)H_ * W_;
    const int c0 = s * CHALF + g * CPG;

    for (int i = t; i < C_; i += NT1) lds_cw1[i] = cw[i];
    if (t < 3 * W_) {
        const int r = t >> 6, col = t & 63;
        const int row = (r == 0) ? hm : ((r == 1) ? h : hp);
        lds_msk[r][col] = mask[((size_t)b * H_ + row) * W_ + col];
    }
    __syncthreads();

    // sum the two channel-half partials, scale, mask
    const size_t r = (size_t)(b * H_ + h);
    const float* sp0 = simp + (r * 2 + 0) * (W_ * 9);
    const float* sp1 = simp + (r * 2 + 1) * (W_ * 9);
    for (int idx = t; idx < W_ * 9; idx += NT1) {
        const int ww = idx / 9, q = idx % 9;
        float v = (sp0[idx] + sp1[idx]) * 0.03952847075210474f;  // 1/sqrt(640)
        const int rq = q / 3, j = q % 3;
        int col = ww + j - 1;
        col = col < 0 ? 0 : (col > W_ - 1 ? W_ - 1 : col);
        if (lds_msk[rq][col] == 1.0f) v = -1e9f;
        lds_attn[ww][q] = v;
    }
    __syncthreads();

    // softmax per pixel (64 threads)
    if (t < W_) {
        float v[9];
        float mx = -3e38f;
        bool valid = false;
        #pragma unroll
        for (int q = 0; q < 9; ++q) {
            v[q] = lds_attn[t][q];
            if (v[q] > -5e8f) valid = true;
            mx = fmaxf(mx, v[q]);
        }
        if (!valid) {
            #pragma unroll
            for (int q = 0; q < 9; ++q) lds_attn[t][q] = 0.f;
        } else {
            float e[9], sum = 0.f;
            #pragma unroll
            for (int q = 0; q < 9; ++q) { e[q] = expf(v[q] - mx); sum += e[q]; }
            const float inv = 1.f / sum;
            #pragma unroll
            for (int q = 0; q < 9; ++q) lds_attn[t][q] = e[q] * inv;
        }
    }
    __syncthreads();

    // displaced per-source sums: 2 shuffles per channel
    float aL[3], aC[3], aR[3];
    #pragma unroll
    for (int rr = 0; rr < 3; ++rr) {
        const float a0 = lds_attn[w][3 * rr];
        const float a1 = lds_attn[w][3 * rr + 1];
        const float a2 = lds_attn[w][3 * rr + 2];
        aC[rr] = a1;
        if (w == 0)      aC[rr] += a0;     // replicate clamp folded into center
        if (w == W_ - 1) aC[rr] += a2;
        aL[rr] = (w < W_ - 1) ? lds_attn[w + 1][3 * rr]     : 0.f;
        aR[rr] = (w > 0)      ? lds_attn[w - 1][3 * rr + 2] : 0.f;
    }
    const int lnL = (w - 1) & 63;
    const int lnR = (w + 1) & 63;

    const float* f0p = Fwp + ((size_t)(b * C_ + c0) * H_ + hm) * W_ + w;
    const float* f1p = Fwp + ((size_t)(b * C_ + c0) * H_ + h ) * W_ + w;
    const float* f2p = Fwp + ((size_t)(b * C_ + c0) * H_ + hp) * W_ + w;
    __hip_bfloat16* fwo = Fww + ((size_t)(b * C_ + c0) * H_ + h) * W_ + w;

    float lamF = 0.f;
    #pragma unroll 8
    for (int k = 0; k < CPG; ++k) {
        float f0 = f0p[k * cs];
        float f1 = f1p[k * cs];
        float f2 = f2p[k * cs];
        float SP = aL[0] * f0 + aL[1] * f1 + aL[2] * f2;   // -> pixel w+1
        float SS = aC[0] * f0 + aC[1] * f1 + aC[2] * f2;   // -> pixel w
        float SM = aR[0] * f0 + aR[1] * f1 + aR[2] * f2;   // -> pixel w-1
        float fwv = __shfl(SP, lnL, 64) + SS + __shfl(SM, lnR, 64);
        fwo[k * cs] = __float2bfloat16(fwv);
        lamF = fmaf(lds_cw1[c0 + k], fwv, lamF);           // pre-rounding value
    }
    lds_red[g][w] = lamF;
    __syncthreads();

    if (t < W_) {
        float v = 0.f;
        #pragma unroll
        for (int gg = 0; gg < G1; ++gg) v += lds_red[gg][t];
        lamFp[(r * 2 + s) * W_ + t] = v;
    }
}

// ===========================================================================
// K3: lam = sigmoid(sum of 4 partials + bias); out = lam*Ft + (1-lam)*Fw
__global__ __launch_bounds__(NT1, 4) void k3_out(
    const float* __restrict__ Ft, const float* __restrict__ cb,
    const float* __restrict__ lamTp, const float* __restrict__ lamFp,
    const __hip_bfloat16* __restrict__ Fww, float* __restrict__ out)
{
    __shared__ float lds_lam[W_];

    const int t = threadIdx.x, w = t & 63, g = t >> 6;
    int b, h, s; decode_bhs(blockIdx.x, b, h, s);
    const size_t cs = (size_t)H_ * W_;
    const int c0 = s * CHALF + g * CPG;

    if (t < W_) {
        const size_t r = (size_t)(b * H_ + h);
        float sd = lamTp[(r * 2 + 0) * W_ + t] + lamTp[(r * 2 + 1) * W_ + t]
                 + lamFp[(r * 2 + 0) * W_ + t] + lamFp[(r * 2 + 1) * W_ + t]
                 + cb[0];
        lds_lam[t] = 1.f / (1.f + expf(-sd));
    }
    __syncthreads();

    const float lam = lds_lam[w];
    const float oml = 1.f - lam;
    const float* ftp = Ft + ((size_t)(b * C_ + c0) * H_ + h) * W_ + w;
    const __hip_bfloat16* fwi = Fww + ((size_t)(b * C_ + c0) * H_ + h) * W_ + w;
    float* outp = out + ((size_t)(b * C_ + c0) * H_ + h) * W_ + w;

    #pragma unroll 8
    for (int k = 0; k < CPG; ++k) {
        const float fwv = __bfloat162float(fwi[k * cs]);
        outp[k * cs] = lam * ftp[k * cs] + oml * fwv;
    }
}

// ===========================================================================
// Fallback: round-3 single fused kernel (used if ws too small).
#define G_  16
#define CPGF 40
#define NT  1024

__global__ __launch_bounds__(NT, 4) void nca_fused(
    const float* __restrict__ Ft,
    const float* __restrict__ Fwp,
    const float* __restrict__ mask,
    const float* __restrict__ cw,
    const float* __restrict__ cb,
    float* __restrict__ out)
{
    __shared__ float lds_cw[2 * C_];
    __shared__ float lds_msk[3][W_];
    __shared__ float lds_sim[G_][W_][9];
    __shared__ float lds_attn[W_][9];
    __shared__ float lds_red[G_][W_];
    __shared__ float lds_lamT[W_];
    __shared__ float lds_lam[W_];
    __shared__ __hip_bfloat16 lds_fw[C_][W_];

    const int t = threadIdx.x;
    const int w = t & 63;
    const int g = t >> 6;

    const int n    = blockIdx.x + gridDim.x * blockIdx.y;
    const int slot = n >> 3;
    const int h = (n & 7) * 8 + (slot & 7);
    const int b = slot >> 3;

    const int hm = (h > 0) ? (h - 1) : 0;
    const int hp = (h < H_ - 1) ? (h + 1) : (H_ - 1);
    const size_t cs = (size_t)H_ * W_;
    const int c0 = g * CPGF;

    for (int i = t; i < 2 * C_; i += NT) lds_cw[i] = cw[i];
    if (t < 3 * W_) {
        const int r = t >> 6, col = t & 63;
        const int row = (r == 0) ? hm : ((r == 1) ? h : hp);
        lds_msk[r][col] = mask[((size_t)b * H_ + row) * W_ + col];
    }
    __syncthreads();

    const float* ftp = Ft  + ((size_t)(b * C_ + c0) * H_ + h ) * W_ + w;
    const float* f0p = Fwp + ((size_t)(b * C_ + c0) * H_ + hm) * W_ + w;
    const float* f1p = Fwp + ((size_t)(b * C_ + c0) * H_ + h ) * W_ + w;
    const float* f2p = Fwp + ((size_t)(b * C_ + c0) * H_ + hp) * W_ + w;

    float sC0=0.f,sC1=0.f,sC2=0.f, sA0=0.f,sA1=0.f,sA2=0.f, sB0=0.f,sB1=0.f,sB2=0.f;
    float lamT = 0.f;
    const int lnL = (w - 1) & 63;
    const int lnR = (w + 1) & 63;

    float ft[CPGF];
    #pragma unroll
    for (int k = 0; k < CPGF; ++k) {
        ft[k]    = ftp[k * cs];
        float f0 = f0p[k * cs];
        float f1 = f1p[k * cs];
        float f2 = f2p[k * cs];
        float ftL = __shfl(ft[k], lnL, 64);
        float ftR = __shfl(ft[k], lnR, 64);
        sC0 = fmaf(ft[k], f0, sC0); sC1 = fmaf(ft[k], f1, sC1); sC2 = fmaf(ft[k], f2, sC2);
        sA0 = fmaf(ftR , f0, sA0); sA1 = fmaf(ftR , f1, sA1); sA2 = fmaf(ftR , f2, sA2);
        sB0 = fmaf(ftL , f0, sB0); sB1 = fmaf(ftL , f1, sB1); sB2 = fmaf(ftL , f2, sB2);
        lamT = fmaf(lds_cw[C_ + c0 + k], ft[k], lamT);
    }

    float simn[9];
    simn[1] = sC0; simn[4] = sC1; simn[7] = sC2;
    simn[0] = __shfl(sA0, lnL, 64);
    simn[3] = __shfl(sA1, lnL, 64);
    simn[6] = __shfl(sA2, lnL, 64);
    simn[2] = __shfl(sB0, lnR, 64);
    simn[5] = __shfl(sB1, lnR, 64);
    simn[8] = __shfl(sB2, lnR, 64);
    if (w == 0)      { simn[0] = sC0; simn[3] = sC1; simn[6] = sC2; }
    if (w == W_ - 1) { simn[2] = sC0; simn[5] = sC1; simn[8] = sC2; }

    #pragma unroll
    for (int q = 0; q < 9; ++q) lds_sim[g][w][q] = simn[q];
    lds_red[g][w] = lamT;
    __syncthreads();

    if (t < W_ * 9) {
        const int ww = t / 9, q = t % 9;
        float sv = 0.f;
        #pragma unroll
        for (int gg = 0; gg < G_; ++gg) sv += lds_sim[gg][ww][q];
        sv *= 0.03952847075210474f;
        const int r = q / 3, j = q % 3;
        int col = ww + j - 1;
        col = col < 0 ? 0 : (col > W_ - 1 ? W_ - 1 : col);
        if (lds_msk[r][col] == 1.0f) sv = -1e9f;
        lds_attn[ww][q] = sv;
    }
    __syncthreads();

    if (t < W_) {
        float v[9];
        float mx = -3e38f;
        bool valid = false;
        #pragma unroll
        for (int q = 0; q < 9; ++q) {
            v[q] = lds_attn[t][q];
            if (v[q] > -5e8f) valid = true;
            mx = fmaxf(mx, v[q]);
        }
        float lt = 0.f;
        #pragma unroll
        for (int gg = 0; gg < G_; ++gg) lt += lds_red[gg][t];
        lds_lamT[t] = lt;
        if (!valid) {
            #pragma unroll
            for (int q = 0; q < 9; ++q) lds_attn[t][q] = 0.f;
        } else {
            float e[9], sum = 0.f;
            #pragma unroll
            for (int q = 0; q < 9; ++q) { e[q] = expf(v[q] - mx); sum += e[q]; }
            const float inv = 1.f / sum;
            #pragma unroll
            for (int q = 0; q < 9; ++q) lds_attn[t][q] = e[q] * inv;
        }
    }
    __syncthreads();

    float aL[3], aC[3], aR[3];
    #pragma unroll
    for (int r = 0; r < 3; ++r) {
        const float a0 = lds_attn[w][3 * r];
        const float a1 = lds_attn[w][3 * r + 1];
        const float a2 = lds_attn[w][3 * r + 2];
        aC[r] = a1;
        if (w == 0)      aC[r] += a0;
        if (w == W_ - 1) aC[r] += a2;
        aL[r] = (w < W_ - 1) ? lds_attn[w + 1][3 * r]     : 0.f;
        aR[r] = (w > 0)      ? lds_attn[w - 1][3 * r + 2] : 0.f;
    }

    float lamF = 0.f;
    #pragma unroll 8
    for (int k = 0; k < CPGF; ++k) {
        float f0 = f0p[k * cs];
        float f1 = f1p[k * cs];
        float f2 = f2p[k * cs];
        float SP = aL[0] * f0 + aL[1] * f1 + aL[2] * f2;
        float SS = aC[0] * f0 + aC[1] * f1 + aC[2] * f2;
        float SM = aR[0] * f0 + aR[1] * f1 + aR[2] * f2;
        float fwv = __shfl(SP, lnL, 64) + SS + __shfl(SM, lnR, 64);
        lds_fw[c0 + k][w] = __float2bfloat16(fwv);
        lamF = fmaf(lds_cw[c0 + k], fwv, lamF);
    }
    lds_red[g][w] = lamF;
    __syncthreads();

    if (t < W_) {
        float sv = lds_lamT[t];
        #pragma unroll
        for (int gg = 0; gg < G_; ++gg) sv += lds_red[gg][t];
        sv += cb[0];
        lds_lam[t] = 1.f / (1.f + expf(-sv));
    }
    __syncthreads();

    const float lam = lds_lam[w];
    const float oml = 1.f - lam;
    float* outp = out + ((size_t)(b * C_ + c0) * H_ + h) * W_ + w;
    #pragma unroll
    for (int k = 0; k < CPGF; ++k) {
        const float fwv = __bfloat162float(lds_fw[c0 + k][w]);
        outp[k * cs] = lam * ft[k] + oml * fwv;
    }
}

// ===========================================================================
extern "C" void kernel_launch(void* const* d_in, const int* in_sizes, int n_in,
                              void* d_out, int out_size, void* d_ws, size_t ws_size,
                              hipStream_t stream) {
    const float* Ft   = (const float*)d_in[0];
    const float* Fwp  = (const float*)d_in[1];
    const float* mask = (const float*)d_in[2];
    const float* cw   = (const float*)d_in[3];
    const float* cb   = (const float*)d_in[4];
    float* out = (float*)d_out;

    // ws layout (floats): simp[B*H*2*W*9] | lamTp[B*H*2*W] | lamFp[...] | Fw bf16
    const size_t n_simp  = (size_t)B_ * H_ * 2 * W_ * 9;   // 294912
    const size_t n_lamp  = (size_t)B_ * H_ * 2 * W_;       // 32768
    const size_t fw_off  = (n_simp + 2 * n_lamp) * 4;      // bytes
    const size_t need    = fw_off + (size_t)B_ * C_ * H_ * W_ * 2;

    if (ws_size >= need) {
        float* simp  = (float*)d_ws;
        float* lamTp = simp + n_simp;
        float* lamFp = lamTp + n_lamp;
        __hip_bfloat16* Fww = (__hip_bfloat16*)((char*)d_ws + fw_off);

        dim3 grid(B_ * H_ * 2);     // 512 blocks = 2 blocks/CU
        dim3 block(NT1);
        k1_sim<<<grid, block, 0, stream>>>(Ft, Fwp, cw, simp, lamTp);
        k2_fw <<<grid, block, 0, stream>>>(Fwp, mask, cw, simp, lamFp, Fww);
        k3_out<<<grid, block, 0, stream>>>(Ft, cb, lamTp, lamFp, Fww, out);
    } else {
        dim3 grid(H_, B_);
        dim3 block(NT);
        nca_fused<<<grid, block, 0, stream>>>(Ft, Fwp, mask, cw, cb, out);
    }
}

// Round 5
// 48.073 us; speedup vs baseline: 1.1863x; 1.1863x over previous
//
#include <hip/hip_runtime.h>
#include <hip/hip_bf16.h>

#define B_  4
#define C_  640
#define H_  64
#define W_  64
#define G_  16          // channel groups (one wave each)
#define CPG 40          // channels per group: G_*CPG == C_
#define NT  1024

__global__ __launch_bounds__(NT, 4) void nca_fused(
    const float* __restrict__ Ft,
    const float* __restrict__ Fwp,
    const float* __restrict__ mask,
    const float* __restrict__ cw,
    const float* __restrict__ cb,
    float* __restrict__ out)
{
    __shared__ float lds_msk[3][W_];            // mask rows hm,h,hp
    __shared__ float lds_sim[G_][W_][9];        // 36 KB sim partials
    __shared__ float lds_attn[W_][9];           // masked sim -> attn (in place)
    __shared__ float lds_red[G_][W_];           // lambda-dot partials
    __shared__ float lds_lamT[W_];
    __shared__ float lds_lam[W_];
    __shared__ __hip_bfloat16 lds_fw[C_][W_];   // 80 KB weighted Fwarp (bf16)

    const int t = threadIdx.x;
    const int w = t & 63;       // lane == pixel column
    const int g = t >> 6;       // channel group == wave id

    // XCD-aware swizzle: XCD x owns rows [x*8, x*8+8) for all batches.
    const int n    = blockIdx.x + gridDim.x * blockIdx.y;
    const int slot = n >> 3;
    const int h = (n & 7) * 8 + (slot & 7);
    const int b = slot >> 3;

    const int hm = (h > 0) ? (h - 1) : 0;
    const int hp = (h < H_ - 1) ? (h + 1) : (H_ - 1);
    const int wm = (w > 0) ? (w - 1) : 0;          // replicate col clamp
    const int wp = (w < W_ - 1) ? (w + 1) : (W_ - 1);
    const size_t cs = (size_t)H_ * W_;
    const int c0 = g * CPG;

    if (t < 3 * W_) {
        const int r = t >> 6, col = t & 63;
        const int row = (r == 0) ? hm : ((r == 1) ? h : hp);
        lds_msk[r][col] = mask[((size_t)b * H_ + row) * W_ + col];
    }
    __syncthreads();

    // 10 per-lane stream pointers: Ft center + 3 rows x 3 col-shifts of Fwarp.
    // Column replicate-pad is folded into the clamped per-lane col offsets.
    const size_t base = (size_t)(b * C_ + c0) * H_;
    const float* ftp = Ft  + (base + h ) * W_ + w;
    const float* q00 = Fwp + (base + hm) * W_ + wm;
    const float* q01 = Fwp + (base + hm) * W_ + w;
    const float* q02 = Fwp + (base + hm) * W_ + wp;
    const float* q10 = Fwp + (base + h ) * W_ + wm;
    const float* q11 = Fwp + (base + h ) * W_ + w;
    const float* q12 = Fwp + (base + h ) * W_ + wp;
    const float* q20 = Fwp + (base + hp) * W_ + wm;
    const float* q21 = Fwp + (base + hp) * W_ + w;
    const float* q22 = Fwp + (base + hp) * W_ + wp;
    const float* cwT = cw + C_ + c0;    // wave-uniform -> scalar loads
    const float* cwF = cw + c0;

    // ---------------- Pass A: sim partials — pure loads + FMA --------------
    float s0=0.f,s1=0.f,s2=0.f,s3=0.f,s4=0.f,s5=0.f,s6=0.f,s7=0.f,s8=0.f;
    float lamT = 0.f;

    for (int k = 0; k < CPG; k += 2) {
        const size_t o0 = (size_t)k * cs, o1 = o0 + cs;
        // 20 independent loads (2 channels staged)
        float fta = ftp[o0], ftb = ftp[o1];
        float a0 = q00[o0], a1 = q01[o0], a2 = q02[o0];
        float a3 = q10[o0], a4 = q11[o0], a5 = q12[o0];
        float a6 = q20[o0], a7 = q21[o0], a8 = q22[o0];
        float b0 = q00[o1], b1 = q01[o1], b2 = q02[o1];
        float b3 = q10[o1], b4 = q11[o1], b5 = q12[o1];
        float b6 = q20[o1], b7 = q21[o1], b8 = q22[o1];
        const float wa = cwT[k], wb = cwT[k + 1];   // uniform scalar loads
        s0 = fmaf(fta, a0, s0); s1 = fmaf(fta, a1, s1); s2 = fmaf(fta, a2, s2);
        s3 = fmaf(fta, a3, s3); s4 = fmaf(fta, a4, s4); s5 = fmaf(fta, a5, s5);
        s6 = fmaf(fta, a6, s6); s7 = fmaf(fta, a7, s7); s8 = fmaf(fta, a8, s8);
        lamT = fmaf(wa, fta, lamT);
        s0 = fmaf(ftb, b0, s0); s1 = fmaf(ftb, b1, s1); s2 = fmaf(ftb, b2, s2);
        s3 = fmaf(ftb, b3, s3); s4 = fmaf(ftb, b4, s4); s5 = fmaf(ftb, b5, s5);
        s6 = fmaf(ftb, b6, s6); s7 = fmaf(ftb, b7, s7); s8 = fmaf(ftb, b8, s8);
        lamT = fmaf(wb, ftb, lamT);
    }

    lds_sim[g][w][0] = s0; lds_sim[g][w][1] = s1; lds_sim[g][w][2] = s2;
    lds_sim[g][w][3] = s3; lds_sim[g][w][4] = s4; lds_sim[g][w][5] = s5;
    lds_sim[g][w][6] = s6; lds_sim[g][w][7] = s7; lds_sim[g][w][8] = s8;
    lds_red[g][w] = lamT;
    __syncthreads();

    // ---------------- reduce across groups + mask --------------------------
    if (t < W_ * 9) {
        const int ww = t / 9, q = t % 9;
        float s = 0.f;
        #pragma unroll
        for (int gg = 0; gg < G_; ++gg) s += lds_sim[gg][ww][q];
        s *= 0.03952847075210474f;          // 1/sqrt(640)
        const int r = q / 3, j = q % 3;
        int col = ww + j - 1;
        col = col < 0 ? 0 : (col > W_ - 1 ? W_ - 1 : col);
        if (lds_msk[r][col] == 1.0f) s = -1e9f;
        lds_attn[ww][q] = s;
    }
    __syncthreads();

    // ---------------- softmax per pixel + lamT reduce ----------------------
    if (t < W_) {
        float v[9];
        float mx = -3e38f;
        bool valid = false;
        #pragma unroll
        for (int q = 0; q < 9; ++q) {
            v[q] = lds_attn[t][q];
            if (v[q] > -5e8f) valid = true;
            mx = fmaxf(mx, v[q]);
        }
        float lt = 0.f;
        #pragma unroll
        for (int gg = 0; gg < G_; ++gg) lt += lds_red[gg][t];
        lds_lamT[t] = lt;
        if (!valid) {
            #pragma unroll
            for (int q = 0; q < 9; ++q) lds_attn[t][q] = 0.f;
        } else {
            float e[9], sum = 0.f;
            #pragma unroll
            for (int q = 0; q < 9; ++q) { e[q] = expf(v[q] - mx); sum += e[q]; }
            const float inv = 1.f / sum;
            #pragma unroll
            for (int q = 0; q < 9; ++q) lds_attn[t][q] = e[q] * inv;
        }
    }
    __syncthreads();

    // ---------------- Pass B: Fw — pure loads + FMA (streams L2-warm) ------
    float at0 = lds_attn[w][0], at1 = lds_attn[w][1], at2 = lds_attn[w][2];
    float at3 = lds_attn[w][3], at4 = lds_attn[w][4], at5 = lds_attn[w][5];
    float at6 = lds_attn[w][6], at7 = lds_attn[w][7], at8 = lds_attn[w][8];

    float lamF = 0.f;
    for (int k = 0; k < CPG; k += 2) {
        const size_t o0 = (size_t)k * cs, o1 = o0 + cs;
        float a0 = q00[o0], a1 = q01[o0], a2 = q02[o0];
        float a3 = q10[o0], a4 = q11[o0], a5 = q12[o0];
        float a6 = q20[o0], a7 = q21[o0], a8 = q22[o0];
        float b0 = q00[o1], b1 = q01[o1], b2 = q02[o1];
        float b3 = q10[o1], b4 = q11[o1], b5 = q12[o1];
        float b6 = q20[o1], b7 = q21[o1], b8 = q22[o1];
        const float wa = cwF[k], wb = cwF[k + 1];
        float fa = at0*a0 + at1*a1 + at2*a2
                 + at3*a3 + at4*a4 + at5*a5
                 + at6*a6 + at7*a7 + at8*a8;
        float fb = at0*b0 + at1*b1 + at2*b2
                 + at3*b3 + at4*b4 + at5*b5
                 + at6*b6 + at7*b7 + at8*b8;
        lds_fw[c0 + k    ][w] = __float2bfloat16(fa);
        lds_fw[c0 + k + 1][w] = __float2bfloat16(fb);
        lamF = fmaf(wa, fa, lamF);
        lamF = fmaf(wb, fb, lamF);
    }
    lds_red[g][w] = lamF;
    __syncthreads();

    // ---------------- lambda = sigmoid(dot + bias) -------------------------
    if (t < W_) {
        float s = lds_lamT[t];
        #pragma unroll
        for (int gg = 0; gg < G_; ++gg) s += lds_red[gg][t];
        s += cb[0];
        lds_lam[t] = 1.f / (1.f + expf(-s));
    }
    __syncthreads();

    // ---------------- Pass C: out = lam*Ft + (1-lam)*Fw (Ft L3-hot) --------
    const float lam = lds_lam[w];
    const float oml = 1.f - lam;
    float* outp = out + (base + h) * W_ + w;
    for (int k = 0; k < CPG; k += 2) {
        const size_t o0 = (size_t)k * cs, o1 = o0 + cs;
        float fta = ftp[o0], ftb = ftp[o1];
        float fwa = __bfloat162float(lds_fw[c0 + k    ][w]);
        float fwb = __bfloat162float(lds_fw[c0 + k + 1][w]);
        outp[o0] = lam * fta + oml * fwa;
        outp[o1] = lam * ftb + oml * fwb;
    }
}

extern "C" void kernel_launch(void* const* d_in, const int* in_sizes, int n_in,
                              void* d_out, int out_size, void* d_ws, size_t ws_size,
                              hipStream_t stream) {
    const float* Ft   = (const float*)d_in[0];
    const float* Fwp  = (const float*)d_in[1];
    const float* mask = (const float*)d_in[2];
    const float* cw   = (const float*)d_in[3];
    const float* cb   = (const float*)d_in[4];
    float* out = (float*)d_out;

    dim3 grid(H_, B_);   // 256 blocks == 256 CUs
    dim3 block(NT);
    nca_fused<<<grid, block, 0, stream>>>(Ft, Fwp, mask, cw, cb, out);
}

// Round 6
// 44.941 us; speedup vs baseline: 1.2690x; 1.0697x over previous
//
#include <hip/hip_runtime.h>
#include <hip/hip_bf16.h>

#define B_  4
#define C_  640
#define H_  64
#define W_  64
#define G_  16          // channel groups (one wave each)
#define CPG 40          // channels per wave: G_*CPG == C_
#define NT  1024

__device__ __forceinline__ unsigned short f2bf(float f) {
    __hip_bfloat16 h = __float2bfloat16(f);
    return __builtin_bit_cast(unsigned short, h);
}
__device__ __forceinline__ float bf2f(unsigned short u) {
    return __bfloat162float(__builtin_bit_cast(__hip_bfloat16, u));
}

// Accumulate one Fwarp row (4 px in r) against ft4 into a[3][4] (q-major).
// Views: vL = cols w-1, vC = cols w, vR = cols w+1 (replicate-clamped).
__device__ __forceinline__ void row_acc(const float4 ft4, const float4 r,
                                        const int l16, float* a) {
    const float pw = __shfl_up(r.w, 1, 64);     // lane l-1's elem 3
    const float nx = __shfl_down(r.x, 1, 64);   // lane l+1's elem 0
    const float vL0 = (l16 == 0)  ? r.x : pw;   // col 0 replicate
    const float vR3 = (l16 == 15) ? r.w : nx;   // col 63 replicate
    a[0]  = fmaf(ft4.x, vL0, a[0]);             // q = col-1
    a[1]  = fmaf(ft4.y, r.x, a[1]);
    a[2]  = fmaf(ft4.z, r.y, a[2]);
    a[3]  = fmaf(ft4.w, r.z, a[3]);
    a[4]  = fmaf(ft4.x, r.x, a[4]);             // q = center
    a[5]  = fmaf(ft4.y, r.y, a[5]);
    a[6]  = fmaf(ft4.z, r.z, a[6]);
    a[7]  = fmaf(ft4.w, r.w, a[7]);
    a[8]  = fmaf(ft4.x, r.y, a[8]);             // q = col+1
    a[9]  = fmaf(ft4.y, r.z, a[9]);
    a[10] = fmaf(ft4.z, r.w, a[10]);
    a[11] = fmaf(ft4.w, vR3, a[11]);
}

// Weighted sum of one Fwarp row into fwv[4]; at = attn[4px][9], r3 = 3*row.
__device__ __forceinline__ void row_fw(const float4 r, const int l16,
                                       const float* at, const int r3,
                                       float* fwv) {
    const float pw = __shfl_up(r.w, 1, 64);
    const float nx = __shfl_down(r.x, 1, 64);
    const float vL0 = (l16 == 0)  ? r.x : pw;
    const float vR3 = (l16 == 15) ? r.w : nx;
    fwv[0] += at[0*9+r3]*vL0 + at[0*9+r3+1]*r.x + at[0*9+r3+2]*r.y;
    fwv[1] += at[1*9+r3]*r.x + at[1*9+r3+1]*r.y + at[1*9+r3+2]*r.z;
    fwv[2] += at[2*9+r3]*r.y + at[2*9+r3+1]*r.z + at[2*9+r3+2]*r.w;
    fwv[3] += at[3*9+r3]*r.z + at[3*9+r3+1]*r.w + at[3*9+r3+2]*vR3;
}

__global__ __launch_bounds__(NT, 4) void nca_fused(
    const float* __restrict__ Ft,
    const float* __restrict__ Fwp,
    const float* __restrict__ mask,
    const float* __restrict__ cw,
    const float* __restrict__ cb,
    float* __restrict__ out)
{
    __shared__ float lds_cw[2 * C_];            // 5 KB
    __shared__ float lds_msk[3][W_];            // 0.75 KB
    __shared__ float lds_sim[G_][W_][9];        // 36 KB
    __shared__ float lds_attn[W_][9];           // 2.25 KB
    __shared__ float lds_red[G_][W_];           // 4 KB
    __shared__ float lds_lamT[W_];
    __shared__ float lds_lam[W_];
    __shared__ __hip_bfloat16 lds_fw[C_][W_];   // 80 KB

    const int t   = threadIdx.x;
    const int l   = t & 63;
    const int g   = t >> 6;
    const int sub = l >> 4;        // channel subgroup 0..3
    const int l16 = l & 15;
    const int w0  = l16 * 4;       // first pixel column of this lane

    // XCD-aware swizzle: XCD x owns rows [x*8, x*8+8) for all batches.
    const int n    = blockIdx.x + gridDim.x * blockIdx.y;
    const int slot = n >> 3;
    const int h = (n & 7) * 8 + (slot & 7);
    const int b = slot >> 3;

    const int hm = (h > 0) ? (h - 1) : 0;
    const int hp = (h < H_ - 1) ? (h + 1) : (H_ - 1);
    const size_t cs = (size_t)H_ * W_;
    const int c0 = g * CPG;

    for (int i = t; i < 2 * C_; i += NT) lds_cw[i] = cw[i];
    if (t < 3 * W_) {
        const int r = t >> 6, col = t & 63;
        const int row = (r == 0) ? hm : ((r == 1) ? h : hp);
        lds_msk[r][col] = mask[((size_t)b * H_ + row) * W_ + col];
    }
    __syncthreads();

    const size_t base = (size_t)(b * C_ + c0) * H_;
    const size_t lo   = (size_t)sub * cs + w0;
    const float* ftp = Ft  + (base + h ) * W_ + lo;
    const float* q0p = Fwp + (base + hm) * W_ + lo;
    const float* q1p = Fwp + (base + h ) * W_ + lo;
    const float* q2p = Fwp + (base + hp) * W_ + lo;

    // ---------------- Pass A: sim partials, float4 per lane ----------------
    float acc[36];                      // [q=0..8][px=0..3], statically indexed
    #pragma unroll
    for (int i = 0; i < 36; ++i) acc[i] = 0.f;
    float lamT[4] = {0.f, 0.f, 0.f, 0.f};

    #pragma unroll 2
    for (int k = 0; k < CPG; k += 4) {
        const size_t off = (size_t)k * cs;
        const float4 ft4 = *(const float4*)(ftp + off);
        const float4 r0  = *(const float4*)(q0p + off);
        const float4 r1  = *(const float4*)(q1p + off);
        const float4 r2  = *(const float4*)(q2p + off);
        const float  wk  = lds_cw[C_ + c0 + k + sub];
        row_acc(ft4, r0, l16, &acc[0]);
        row_acc(ft4, r1, l16, &acc[12]);
        row_acc(ft4, r2, l16, &acc[24]);
        lamT[0] = fmaf(wk, ft4.x, lamT[0]);
        lamT[1] = fmaf(wk, ft4.y, lamT[1]);
        lamT[2] = fmaf(wk, ft4.z, lamT[2]);
        lamT[3] = fmaf(wk, ft4.w, lamT[3]);
    }

    // reduce the 4 channel-subgroups (lanes l, l^16, l^32, l^48)
    #pragma unroll
    for (int i = 0; i < 36; ++i) {
        acc[i] += __shfl_xor(acc[i], 16, 64);
        acc[i] += __shfl_xor(acc[i], 32, 64);
    }
    #pragma unroll
    for (int px = 0; px < 4; ++px) {
        lamT[px] += __shfl_xor(lamT[px], 16, 64);
        lamT[px] += __shfl_xor(lamT[px], 32, 64);
    }

    if (l < 16) {
        #pragma unroll
        for (int px = 0; px < 4; ++px) {
            const int ww = w0 + px;
            #pragma unroll
            for (int rr = 0; rr < 3; ++rr) {      // acc is q-major [3r+cc][px]
                lds_sim[g][ww][3*rr+0] = acc[(3*rr+0)*4 + px];
                lds_sim[g][ww][3*rr+1] = acc[(3*rr+1)*4 + px];
                lds_sim[g][ww][3*rr+2] = acc[(3*rr+2)*4 + px];
            }
            lds_red[g][ww] = lamT[px];
        }
    }
    __syncthreads();

    // ---------------- reduce across waves + mask ---------------------------
    if (t < W_ * 9) {
        const int ww = t / 9, q = t % 9;
        float s = 0.f;
        #pragma unroll
        for (int gg = 0; gg < G_; ++gg) s += lds_sim[gg][ww][q];
        s *= 0.03952847075210474f;          // 1/sqrt(640)
        const int r = q / 3, j = q % 3;
        int col = ww + j - 1;
        col = col < 0 ? 0 : (col > W_ - 1 ? W_ - 1 : col);
        if (lds_msk[r][col] == 1.0f) s = -1e9f;
        lds_attn[ww][q] = s;
    }
    __syncthreads();

    // ---------------- softmax per pixel + lamT reduce ----------------------
    if (t < W_) {
        float v[9];
        float mx = -3e38f;
        bool valid = false;
        #pragma unroll
        for (int q = 0; q < 9; ++q) {
            v[q] = lds_attn[t][q];
            if (v[q] > -5e8f) valid = true;
            mx = fmaxf(mx, v[q]);
        }
        float lt = 0.f;
        #pragma unroll
        for (int gg = 0; gg < G_; ++gg) lt += lds_red[gg][t];
        lds_lamT[t] = lt;
        if (!valid) {
            #pragma unroll
            for (int q = 0; q < 9; ++q) lds_attn[t][q] = 0.f;
        } else {
            float e[9], sum = 0.f;
            #pragma unroll
            for (int q = 0; q < 9; ++q) { e[q] = expf(v[q] - mx); sum += e[q]; }
            const float inv = 1.f / sum;
            #pragma unroll
            for (int q = 0; q < 9; ++q) lds_attn[t][q] = e[q] * inv;
        }
    }
    __syncthreads();

    // ---------------- Pass B: Fw, float4 per lane ---------------------------
    float at[36];                        // attn[px][q], statically indexed
    #pragma unroll
    for (int px = 0; px < 4; ++px)
        #pragma unroll
        for (int q = 0; q < 9; ++q) at[px*9+q] = lds_attn[w0+px][q];

    float lamF[4] = {0.f, 0.f, 0.f, 0.f};
    #pragma unroll 2
    for (int k = 0; k < CPG; k += 4) {
        const size_t off = (size_t)k * cs;
        const float4 r0 = *(const float4*)(q0p + off);
        const float4 r1 = *(const float4*)(q1p + off);
        const float4 r2 = *(const float4*)(q2p + off);
        float fwv[4] = {0.f, 0.f, 0.f, 0.f};
        row_fw(r0, l16, at, 0, fwv);
        row_fw(r1, l16, at, 3, fwv);
        row_fw(r2, l16, at, 6, fwv);
        const int c = c0 + k + sub;
        ushort4 us;
        us.x = f2bf(fwv[0]); us.y = f2bf(fwv[1]);
        us.z = f2bf(fwv[2]); us.w = f2bf(fwv[3]);
        *(ushort4*)(&lds_fw[c][w0]) = us;
        const float wk = lds_cw[c];
        lamF[0] = fmaf(wk, fwv[0], lamF[0]);
        lamF[1] = fmaf(wk, fwv[1], lamF[1]);
        lamF[2] = fmaf(wk, fwv[2], lamF[2]);
        lamF[3] = fmaf(wk, fwv[3], lamF[3]);
    }
    #pragma unroll
    for (int px = 0; px < 4; ++px) {
        lamF[px] += __shfl_xor(lamF[px], 16, 64);
        lamF[px] += __shfl_xor(lamF[px], 32, 64);
    }
    if (l < 16) {
        #pragma unroll
        for (int px = 0; px < 4; ++px) lds_red[g][w0+px] = lamF[px];
    }
    __syncthreads();

    // ---------------- lambda = sigmoid(dot + bias) -------------------------
    if (t < W_) {
        float s = lds_lamT[t];
        #pragma unroll
        for (int gg = 0; gg < G_; ++gg) s += lds_red[gg][t];
        s += cb[0];
        lds_lam[t] = 1.f / (1.f + expf(-s));
    }
    __syncthreads();

    // ---------------- Pass C: blend + store, float4 ------------------------
    float lam4[4], oml4[4];
    #pragma unroll
    for (int px = 0; px < 4; ++px) {
        lam4[px] = lds_lam[w0 + px];
        oml4[px] = 1.f - lam4[px];
    }
    float* outp = out + (base + h) * W_ + lo;
    #pragma unroll 2
    for (int k = 0; k < CPG; k += 4) {
        const size_t off = (size_t)k * cs;
        const float4 ft4 = *(const float4*)(ftp + off);
        const ushort4 us = *(const ushort4*)(&lds_fw[c0 + k + sub][w0]);
        float4 o;
        o.x = lam4[0] * ft4.x + oml4[0] * bf2f(us.x);
        o.y = lam4[1] * ft4.y + oml4[1] * bf2f(us.y);
        o.z = lam4[2] * ft4.z + oml4[2] * bf2f(us.z);
        o.w = lam4[3] * ft4.w + oml4[3] * bf2f(us.w);
        *(float4*)(outp + off) = o;
    }
}

extern "C" void kernel_launch(void* const* d_in, const int* in_sizes, int n_in,
                              void* d_out, int out_size, void* d_ws, size_t ws_size,
                              hipStream_t stream) {
    const float* Ft   = (const float*)d_in[0];
    const float* Fwp  = (const float*)d_in[1];
    const float* mask = (const float*)d_in[2];
    const float* cw   = (const float*)d_in[3];
    const float* cb   = (const float*)d_in[4];
    float* out = (float*)d_out;

    dim3 grid(H_, B_);   // 256 blocks == 256 CUs
    dim3 block(NT);
    nca_fused<<<grid, block, 0, stream>>>(Ft, Fwp, mask, cw, cb, out);
}